// Round 6
// baseline (307.637 us; speedup 1.0000x reference)
//
#include <hip/hip_runtime.h>
#include <hip/hip_bf16.h>

// B=4096, L=50, D=64, E=128, CAT=384, U=256, V=100000. fp32 I/O, int32 ids.
// Factored: h = relu(qvec + [K|K*q]·[W_k;W_qk]);  qvec = b_hide + q·W_q
// scores = (h·W_out + b_out)*mask ; out = scores·K
//
// Structure: 1024 blocks × 4 batches, software-pipelined (gathers for b_{i+1}
// issued before b_i's MFMA). Weights packed in MFMA-fragment order
// g_Wp[kk8][n][8]. R6 fix: LDS stores now cover ALL 32 cols per thread
// (R5 wrote 8 of each 16 — half of Kb/A2 was uninitialized garbage → NaN).

#define L_SEQ 50
#define LP    64
#define D_EMB 64
#define E_DIM 128
#define U_DIM 256
#define V_SZ  100000
#define KSTR  136   // LDS row stride (bf16): rows 16B-aligned
#define NB    4     // batches per block

typedef __bf16 bf16x8 __attribute__((ext_vector_type(8)));
typedef float  f32x4  __attribute__((ext_vector_type(4)));

// packed weights: g_Wp[kk8*2048 + n*8 + j] = bf16(W_hide[kk8*8+j][n]), kk8<48
// kk8 0..15 -> W_q rows (qvec);  kk8 16..47 -> [W_k;W_qk] rows (B-fragments)
__device__ __bf16 g_Wp[48 * 256 * 8];

__global__ __launch_bounds__(256) void pack_kernel(const float* __restrict__ W) {
  int e = blockIdx.x * 256 + threadIdx.x;          // grid 384 -> exact cover
  int kk8 = e >> 11, rem = e & 2047, n = rem >> 3, j = rem & 7;
  g_Wp[e] = (__bf16)W[(kk8 * 8 + j) * 256 + n];
}

__global__ __launch_bounds__(256, 3) void din_main_kernel(
    const int* __restrict__ qid_item, const int* __restrict__ qid_cate,
    const int* __restrict__ seq_item, const int* __restrict__ seq_cate,
    const int* __restrict__ mask,
    const float* __restrict__ emb_item,
    const float* __restrict__ emb_cate,
    const float* __restrict__ b_hide,
    const float* __restrict__ W_out,
    const float* __restrict__ b_out,
    float* __restrict__ out) {
  __shared__ alignas(16) __bf16 Kb[LP * KSTR];     // bf16(K)      17408 B
  __shared__ alignas(16) __bf16 A2[LP * KSTR];     // bf16(K*q)    17408 B
  __shared__ alignas(16) float qrowf[2][E_DIM];    // fp32 q, double-buffered
  __shared__ float qv_s[U_DIM];
  __shared__ float scpart[4][LP];
  __shared__ float scores[LP];

  const int t = threadIdx.x;
  const int b0 = blockIdx.x * NB;
  const int r = t >> 2, q4 = t & 3;
  const int col0 = q4 * 32;
  const int wave = t >> 6, lane = t & 63;
  const int m = lane & 15, quad = lane >> 4;

  // ---- prologue: ids, masks, small params (uniform regs) ----
  int sid[NB], qiid[NB];
  float mskf[NB];
#pragma unroll
  for (int i = 0; i < NB; ++i) {
    sid[i] = 0;
    if (r < L_SEQ) {
      int id = (q4 < 2 ? seq_item : seq_cate)[(b0 + i) * L_SEQ + r];
      sid[i] = ((unsigned)id < (unsigned)V_SZ) ? id : 0;
    }
    mskf[i] = 0.f;
    if (t < L_SEQ) mskf[i] = (mask[(b0 + i) * L_SEQ + t] != 0) ? 1.f : 0.f;
    qiid[i] = 0;
    if (t < 32) {
      int id = (t < 16 ? qid_item : qid_cate)[b0 + i];
      qiid[i] = ((unsigned)id < (unsigned)V_SZ) ? id : 0;
    }
  }
  float wo_r[4];
#pragma unroll
  for (int nt = 0; nt < 4; ++nt) wo_r[nt] = W_out[wave * 64 + nt * 16 + m];
  const float bh_r = b_hide[t];
  const float bo_r = b_out[0];
  const float vsel = (r < L_SEQ) ? 1.f : 0.f;   // zero pad rows 50..63

  const float* embsel  = (q4 < 2) ? emb_item : emb_cate;
  const float* qembsel = (t < 16) ? emb_item : emb_cate;
  const int qcol = (t < 16) ? t * 4 : 64 + (t - 16) * 4;

  // ---- issue gathers for b0 ----
  float4 kvf[8], qbuf;
  {
    const float4* src = (const float4*)(embsel + (size_t)sid[0] * D_EMB + (q4 & 1) * 32);
#pragma unroll
    for (int jj = 0; jj < 8; ++jj) kvf[jj] = src[jj];
    if (t < 32)
      qbuf = *(const float4*)(qembsel + (size_t)qiid[0] * D_EMB + (t & 15) * 4);
  }
  if (t < 32) *(float4*)&qrowf[0][qcol] = qbuf;
  __syncthreads();   // qrowf[0] visible

#pragma unroll
  for (int i = 0; i < NB; ++i) {
    const int cur = i & 1;
    // ---- store Kb + A2 from kvf regs; q from LDS. FULL 32-col coverage:
    //      per h, 16 values -> two bf16x8 stores (R6 fix). ----
    const float* qc = &qrowf[cur][col0];
#pragma unroll
    for (int h = 0; h < 2; ++h) {
      bf16x8 kb0, kb1, ab0, ab1;
#pragma unroll
      for (int jj = 0; jj < 2; ++jj) {   // first 8 of this 16-col half
        float4 kf = kvf[h * 4 + jj];
        float4 qf = ((const float4*)qc)[h * 4 + jj];
        kb0[jj * 4 + 0] = (__bf16)(kf.x * vsel);
        kb0[jj * 4 + 1] = (__bf16)(kf.y * vsel);
        kb0[jj * 4 + 2] = (__bf16)(kf.z * vsel);
        kb0[jj * 4 + 3] = (__bf16)(kf.w * vsel);
        ab0[jj * 4 + 0] = (__bf16)(kf.x * qf.x * vsel);
        ab0[jj * 4 + 1] = (__bf16)(kf.y * qf.y * vsel);
        ab0[jj * 4 + 2] = (__bf16)(kf.z * qf.z * vsel);
        ab0[jj * 4 + 3] = (__bf16)(kf.w * qf.w * vsel);
      }
#pragma unroll
      for (int jj = 0; jj < 2; ++jj) {   // second 8
        float4 kf = kvf[h * 4 + 2 + jj];
        float4 qf = ((const float4*)qc)[h * 4 + 2 + jj];
        kb1[jj * 4 + 0] = (__bf16)(kf.x * vsel);
        kb1[jj * 4 + 1] = (__bf16)(kf.y * vsel);
        kb1[jj * 4 + 2] = (__bf16)(kf.z * vsel);
        kb1[jj * 4 + 3] = (__bf16)(kf.w * vsel);
        ab1[jj * 4 + 0] = (__bf16)(kf.x * qf.x * vsel);
        ab1[jj * 4 + 1] = (__bf16)(kf.y * qf.y * vsel);
        ab1[jj * 4 + 2] = (__bf16)(kf.z * qf.z * vsel);
        ab1[jj * 4 + 3] = (__bf16)(kf.w * qf.w * vsel);
      }
      *(bf16x8*)&Kb[r * KSTR + col0 + h * 16]     = kb0;
      *(bf16x8*)&Kb[r * KSTR + col0 + h * 16 + 8] = kb1;
      *(bf16x8*)&A2[r * KSTR + col0 + h * 16]     = ab0;
      *(bf16x8*)&A2[r * KSTR + col0 + h * 16 + 8] = ab1;
    }
    __syncthreads();   // B1: Kb/A2 ready

    // ---- issue gathers for b_{i+1} (hidden behind MFMA below) ----
    if (i + 1 < NB) {
      const float4* src =
          (const float4*)(embsel + (size_t)sid[i + 1] * D_EMB + (q4 & 1) * 32);
#pragma unroll
      for (int jj = 0; jj < 8; ++jj) kvf[jj] = src[jj];
      if (t < 32)
        qbuf = *(const float4*)(qembsel + (size_t)qiid[i + 1] * D_EMB + (t & 15) * 4);
    }

    // ---- qvec: qv_s[t] = b_hide[t] + sum_c q[c]*W_q[c][t] (coalesced) ----
    {
      float accq = bh_r;
#pragma unroll
      for (int c8 = 0; c8 < 16; ++c8) {
        bf16x8 w8 = *(const bf16x8*)&g_Wp[(c8 << 11) + t * 8];
        float4 qa = *(const float4*)&qrowf[cur][c8 * 8];
        float4 qb = *(const float4*)&qrowf[cur][c8 * 8 + 4];
        accq += qa.x * (float)w8[0] + qa.y * (float)w8[1] +
                qa.z * (float)w8[2] + qa.w * (float)w8[3] +
                qb.x * (float)w8[4] + qb.y * (float)w8[5] +
                qb.z * (float)w8[6] + qb.w * (float)w8[7];
      }
      qv_s[t] = accq;
    }

    // ---- MFMA: M=64 (4 mt), N=64/wave (4 nt), K=256 (8 s) ----
    f32x4 acc[4][4];
#pragma unroll
    for (int mt = 0; mt < 4; ++mt)
#pragma unroll
      for (int nt = 0; nt < 4; ++nt) acc[mt][nt] = (f32x4){0.f, 0.f, 0.f, 0.f};
#pragma unroll
    for (int s = 0; s < 8; ++s) {
      const __bf16* Ab = (s < 4) ? Kb : A2;
      const int klocal = (s & 3) * 32 + quad * 8;
      bf16x8 afr[4], bfr[4];
#pragma unroll
      for (int mt = 0; mt < 4; ++mt)
        afr[mt] = *(const bf16x8*)&Ab[(mt * 16 + m) * KSTR + klocal];
#pragma unroll
      for (int nt = 0; nt < 4; ++nt)
        bfr[nt] = *(const bf16x8*)
            &g_Wp[((16 + s * 4 + quad) << 11) + (wave * 64 + nt * 16 + m) * 8];
#pragma unroll
      for (int mt = 0; mt < 4; ++mt)
#pragma unroll
        for (int nt = 0; nt < 4; ++nt)
          acc[mt][nt] = __builtin_amdgcn_mfma_f32_16x16x32_bf16(
              afr[mt], bfr[nt], acc[mt][nt], 0, 0, 0);
    }
    __syncthreads();   // B2: qv_s visible

    // ---- epilogue: h=relu(acc+qv); score partials = h·W_out ----
    float qv[4];
#pragma unroll
    for (int nt = 0; nt < 4; ++nt) qv[nt] = qv_s[wave * 64 + nt * 16 + m];
    float part[16];
#pragma unroll
    for (int mt = 0; mt < 4; ++mt)
#pragma unroll
      for (int rg = 0; rg < 4; ++rg) {
        float sum = 0.f;
#pragma unroll
        for (int nt = 0; nt < 4; ++nt) {
          float h = acc[mt][nt][rg] + qv[nt];
          h = fmaxf(h, 0.f);
          sum += h * wo_r[nt];
        }
        part[mt * 4 + rg] = sum;
      }
#pragma unroll
    for (int off = 1; off < 16; off <<= 1)
#pragma unroll
      for (int k = 0; k < 16; ++k)
        part[k] += __shfl_xor(part[k], off, 64);
    if (m == 0) {
#pragma unroll
      for (int mt = 0; mt < 4; ++mt)
#pragma unroll
        for (int rg = 0; rg < 4; ++rg)
          scpart[wave][mt * 16 + quad * 4 + rg] = part[mt * 4 + rg];
    }
    __syncthreads();   // B3: scpart ready
    if (t < LP) {
      float sc = scpart[0][t] + scpart[1][t] + scpart[2][t] + scpart[3][t] + bo_r;
      scores[t] = sc * mskf[i];
    }
    if (i + 1 < NB && t < 32)
      *(float4*)&qrowf[(i + 1) & 1][qcol] = qbuf;   // q for next batch
    __syncthreads();   // B4: scores + next qrowf visible
    if (t < E_DIM) {
      float o = 0.f;
#pragma unroll
      for (int l = 0; l < L_SEQ; ++l)
        o += scores[l] * (float)Kb[l * KSTR + t];
      out[(size_t)(b0 + i) * E_DIM + t] = o;
    }
    __syncthreads();   // B5: Kb free for next batch's stores
  }
}

extern "C" void kernel_launch(void* const* d_in, const int* in_sizes, int n_in,
                              void* d_out, int out_size, void* d_ws, size_t ws_size,
                              hipStream_t stream) {
  const int* qid_item = (const int*)d_in[0];
  const int* qid_cate = (const int*)d_in[1];
  const int* seq_item = (const int*)d_in[2];
  const int* seq_cate = (const int*)d_in[3];
  const int* mask     = (const int*)d_in[4];
  const float* emb_item = (const float*)d_in[5];
  const float* emb_cate = (const float*)d_in[6];
  const float* W_hide   = (const float*)d_in[7];
  const float* b_hide   = (const float*)d_in[8];
  const float* W_out    = (const float*)d_in[9];
  const float* b_out    = (const float*)d_in[10];
  float* out = (float*)d_out;

  (void)d_ws; (void)ws_size;

  pack_kernel<<<384, 256, 0, stream>>>(W_hide);
  din_main_kernel<<<4096 / NB, 256, 0, stream>>>(
      qid_item, qid_cate, seq_item, seq_cate, mask, emb_item, emb_cate,
      b_hide, W_out, b_out, out);
}